// Round 5
// baseline (112.117 us; speedup 1.0000x reference)
//
#include <hip/hip_runtime.h>
#include <hip/hip_bf16.h>
#include <hip/hip_fp16.h>
#include <math.h>

// Problem constants: B=16, L=96, H=128.
#define BB 16
#define LL 96
#define HH 128

typedef __attribute__((ext_vector_type(8))) short short8;
typedef __attribute__((ext_vector_type(4))) float f32x4;

// ws byte offsets:
//  WS_W : bf16 W slice [i][o][e ^ ((o&7)<<3)]          -> 2,359,296 B
//  WS_E : dual-copy bf16 padded enc rows [b][i][272u32] -> 1,671,168 B
//  WS_DEC/WS_CVG/WS_SC : fp32 dec_f / cvg_f / scores
//  WS_CNT: per-b completion counters (int)
//  WS_P : fp16 partials [kc][b][o][w]                   -> 12,582,912 B
#define WS_W_OFF   0
#define WS_E_OFF   2359296
#define WS_DEC_OFF 4030464
#define WS_CVG_OFF 4038656
#define WS_SC_OFF  4044800
#define WS_CNT_OFF 4050944
#define WS_P_OFF   4051008

// ---------------- P: repack W->bf16 swizzled, dual enc rows, dec_f, cvg_f, zero counters ----
__global__ __launch_bounds__(256) void prep_kernel(
        const float* __restrict__ hidden,
        const float* __restrict__ enc,
        const float* __restrict__ coverage,
        const float* __restrict__ attn_w,
        const float* __restrict__ cvg_w,
        const float* __restrict__ cvg_b,
        const float* __restrict__ dec_w,
        const float* __restrict__ dec_b,
        char* __restrict__ wsb) {
    const int bid = blockIdx.x;
    const int tid = threadIdx.x;
    if (bid < 96) {
        // W slice kh=63: ws_W[i][o][e] = bf16(attn_w[o][i][63][ e ^ ((o&7)<<3) ])
        const int i = bid;
        unsigned short* wout = (unsigned short*)(wsb + WS_W_OFF);
        for (int idx = tid; idx < LL * HH; idx += 256) {
            const int o = idx >> 7, e = idx & 127;
            const int esrc = e ^ ((o & 7) << 3);
            float v = attn_w[(((size_t)o * LL + i) * HH + 63) * HH + esrc];
            __hip_bfloat16 h = __float2bfloat16(v);
            wout[(size_t)i * LL * HH + idx] = *(unsigned short*)&h;
        }
    } else if (bid < 112) {
        // dual-copy bf16 padded enc rows, per row 272 u32:
        //  [0..127]   w0[q] = (e(2q),   e(2q+1))
        //  [129..256] w1[q] = (e(2q+1), e(2q+2));  e(t)=enc[t-63] for t in [63,191) else 0
        const int b = bid - 96;
        unsigned int* eout = (unsigned int*)(wsb + WS_E_OFF) + (size_t)b * LL * 272;
        const float* esrc = enc + (size_t)b * LL * HH;
        for (int idx = tid; idx < LL * 272; idx += 256) {
            const int i = idx / 272, c = idx % 272;
            int t0 = -1, t1 = -1;
            if (c < 128) { t0 = 2 * c; t1 = 2 * c + 1; }
            else if (c >= 129 && c < 257) { int q = c - 129; t0 = 2 * q + 1; t1 = 2 * q + 2; }
            unsigned int lo16 = 0, hi16 = 0;
            if (t0 >= 63 && t0 < 191) {
                __hip_bfloat16 h = __float2bfloat16(esrc[i * HH + t0 - 63]);
                lo16 = *(unsigned short*)&h;
            }
            if (t1 >= 63 && t1 < 191) {
                __hip_bfloat16 h = __float2bfloat16(esrc[i * HH + t1 - 63]);
                hi16 = *(unsigned short*)&h;
            }
            eout[idx] = lo16 | (hi16 << 16);
        }
    } else {
        const int b = bid - 112;
        float* decf = (float*)(wsb + WS_DEC_OFF);
        float* cvgf = (float*)(wsb + WS_CVG_OFF);
        __shared__ float hid[HH];
        __shared__ float cov[LL];
        if (tid < HH) hid[tid] = hidden[b * HH + tid];
        if (tid < LL) cov[tid] = coverage[b * LL + tid];
        if (tid == 255)
            __hip_atomic_store((int*)(wsb + WS_CNT_OFF) + b, 0,
                               __ATOMIC_RELAXED, __HIP_MEMORY_SCOPE_AGENT);
        __syncthreads();
        if (tid < HH) {
            float acc = dec_b[tid];
            for (int k = 0; k < HH; ++k) acc += hid[k] * dec_w[tid * HH + k];
            decf[b * HH + tid] = acc;
        } else if (tid < HH + LL) {
            const int t = tid - HH;
            float a2 = cvg_b[t];
            for (int i2 = 0; i2 < LL; ++i2)
                a2 += cov[i2] * cvg_w[((size_t)t * LL + i2) * HH + 63];
            cvgf[b * LL + t] = a2;
        }
    }
}

// ---------------- M: bf16 MFMA, round-3 topology (4 w-split waves) ----------------
// grid (kc=32, b=16) x 256 thr. Per block: 3 i-rows, K=384.
// A staged 24KB/row via global_load_lds (double-buffered); B from dual-copy LDS row.
__global__ __launch_bounds__(256) void mfma_kernel(char* __restrict__ wsb) {
    const int kc = blockIdx.x;   // 0..31
    const int b  = blockIdx.y;   // 0..15
    const int tid  = threadIdx.x;
    const int lane = tid & 63;
    const int wg   = tid >> 6;   // wave id 0..3 (w-split)
    const int lo   = lane & 15;
    const int hi   = lane >> 4;  // 0..3

    __shared__ __align__(16) short Abuf[2][LL * HH];          // 2 x 24KB
    __shared__ __align__(16) unsigned int Ebuf[2][272];       // 2 x 1088B

    const char* wbase = wsb + WS_W_OFF;
    const unsigned int* esrc = (const unsigned int*)(wsb + WS_E_OFF)
                               + ((size_t)b * LL + kc * 3) * 272;
    __half* Pp = (__half*)(wsb + WS_P_OFF);

    f32x4 acc[6][2];
#pragma unroll
    for (int ot = 0; ot < 6; ++ot)
#pragma unroll
        for (int wt = 0; wt < 2; ++wt) acc[ot][wt] = f32x4{0.f, 0.f, 0.f, 0.f};

    auto stageA = [&](int r, int buf) {
        const char* gA = wbase + (size_t)(kc * 3 + r) * (LL * HH * 2);
        char* lA = (char*)&Abuf[buf][0];
#pragma unroll
        for (int c = 0; c < 6; ++c) {
            __builtin_amdgcn_global_load_lds(
                (const __attribute__((address_space(1))) void*)(gA + c * 4096 + tid * 16),
                (__attribute__((address_space(3))) void*)(lA + c * 4096 + wg * 1024),
                16, 0, 0);
        }
    };
    auto stageE = [&](int r, int buf) {
        if (tid < 68) {
            uint4 v = *(const uint4*)(esrc + r * 272 + tid * 4);
            *(uint4*)&Ebuf[buf][tid * 4] = v;
        }
    };
    auto compute = [&](int buf) {
        const short8* A8 = (const short8*)&Abuf[buf][0];
        const unsigned int* row = &Ebuf[buf][0];
#pragma unroll
        for (int s = 0; s < 4; ++s) {
            short8 af[6];
#pragma unroll
            for (int ot = 0; ot < 6; ++ot) {
                const int o = ot * 16 + lo;
                af[ot] = A8[o * 16 + (((s << 2) + hi) ^ (lo & 7))];
            }
#pragma unroll
            for (int wt = 0; wt < 2; ++wt) {
                const int t0 = s * 32 + hi * 8 + wg * 32 + wt * 16 + lo;
                const unsigned int* arr = row + ((lo & 1) ? 129 : 0) + (t0 >> 1);
                union { uint4 u; short8 s8; } bf;
                bf.u.x = arr[0]; bf.u.y = arr[1]; bf.u.z = arr[2]; bf.u.w = arr[3];
#pragma unroll
                for (int ot = 0; ot < 6; ++ot)
                    acc[ot][wt] = __builtin_amdgcn_mfma_f32_16x16x32_bf16(
                        af[ot], bf.s8, acc[ot][wt], 0, 0, 0);
            }
        }
    };

    stageA(0, 0); stageE(0, 0);
    __syncthreads();
    stageA(1, 1); stageE(1, 1);       // prefetch r1 while computing r0
    compute(0);
    __syncthreads();
    stageA(2, 0); stageE(2, 0);       // prefetch r2 while computing r1
    compute(1);
    __syncthreads();
    compute(0);

    // fp16 partial store, [kc][b][o][w], w lane-consecutive -> coalesced
#pragma unroll
    for (int ot = 0; ot < 6; ++ot)
#pragma unroll
        for (int wt = 0; wt < 2; ++wt) {
            const int w = wg * 32 + wt * 16 + lo;
#pragma unroll
            for (int r = 0; r < 4; ++r) {
                const int o = ot * 16 + hi * 4 + r;
                Pp[((size_t)(kc * BB + b) * LL + o) * HH + w] =
                    __float2half(acc[ot][wt][r]);
            }
        }
}

// ---------------- RF: sum partials -> tanh.v -> score; last block per b does softmax+outputs ----
__global__ __launch_bounds__(128) void reduceF_kernel(
        const float* __restrict__ attn_b,
        const float* __restrict__ vvec,
        const float* __restrict__ coverage,
        const float* __restrict__ enc,
        char* __restrict__ wsb,
        float* __restrict__ out) {
    const int o = blockIdx.x;   // 0..95
    const int b = blockIdx.y;   // 0..15
    const int h = threadIdx.x;  // 0..127
    const __half* p = (const __half*)(wsb + WS_P_OFF) + ((size_t)b * LL + o) * HH + h;
    const float* dec = (const float*)(wsb + WS_DEC_OFF);
    const float* cvg = (const float*)(wsb + WS_CVG_OFF);
    float* sc_ws = (float*)(wsb + WS_SC_OFF);
    int* cnt = (int*)(wsb + WS_CNT_OFF);

    float sum = 0.f;
#pragma unroll
    for (int kc = 0; kc < 32; ++kc)
        sum += __half2float(p[(size_t)kc * BB * LL * HH]);
    float ef = sum + attn_b[o] + dec[b * HH + h] + cvg[b * LL + o];
    float s = tanhf(ef) * vvec[b * HH + h];
#pragma unroll
    for (int off = 32; off > 0; off >>= 1) s += __shfl_down(s, off, 64);

    __shared__ float r2[2];
    __shared__ int isLast;
    if ((h & 63) == 0) r2[h >> 6] = s;
    __syncthreads();
    if (h == 0) {
        float sc = r2[0] + r2[1];
        __hip_atomic_store(&sc_ws[b * LL + o], sc,
                           __ATOMIC_RELEASE, __HIP_MEMORY_SCOPE_AGENT);
        int old = __hip_atomic_fetch_add(&cnt[b], 1,
                                         __ATOMIC_ACQ_REL, __HIP_MEMORY_SCOPE_AGENT);
        isLast = (old == LL - 1);
    }
    __syncthreads();
    if (!isLast) return;

    // tail: softmax + all three outputs for batch b
    __shared__ float scl[LL], atl[LL];
    if (h < LL)
        scl[h] = __hip_atomic_load(&sc_ws[b * LL + h],
                                   __ATOMIC_ACQUIRE, __HIP_MEMORY_SCOPE_AGENT);
    __syncthreads();
    float mx = -1e30f;
    for (int l = 0; l < LL; ++l) mx = fmaxf(mx, scl[l]);
    float den = 0.f;
    for (int l = 0; l < LL; ++l) den += expf(scl[l] - mx);
    if (h < LL) {
        float a = expf(scl[h] - mx) / den;
        atl[h] = a;
        out[BB * HH + b * LL + h] = a;                                   // attn
        out[BB * HH + BB * LL + b * LL + h] = coverage[b * LL + h] + a;  // new_coverage
    }
    __syncthreads();
    float c = 0.f;
    for (int l = 0; l < LL; ++l) c += atl[l] * enc[((size_t)b * LL + l) * HH + h];
    out[b * HH + h] = c;                                                 // context
}

extern "C" void kernel_launch(void* const* d_in, const int* in_sizes, int n_in,
                              void* d_out, int out_size, void* d_ws, size_t ws_size,
                              hipStream_t stream) {
    const float* hidden   = (const float*)d_in[0];
    const float* enc      = (const float*)d_in[1];
    const float* coverage = (const float*)d_in[2];
    const float* attn_w   = (const float*)d_in[3];
    const float* attn_b   = (const float*)d_in[4];
    const float* cvg_w    = (const float*)d_in[5];
    const float* cvg_b    = (const float*)d_in[6];
    const float* dec_w    = (const float*)d_in[7];
    const float* dec_b    = (const float*)d_in[8];
    const float* vvec     = (const float*)d_in[9];
    float* out = (float*)d_out;
    char* wsb = (char*)d_ws;

    prep_kernel<<<128, 256, 0, stream>>>(hidden, enc, coverage, attn_w,
                                         cvg_w, cvg_b, dec_w, dec_b, wsb);
    mfma_kernel<<<dim3(32, BB), 256, 0, stream>>>(wsb);
    reduceF_kernel<<<dim3(LL, BB), 128, 0, stream>>>(attn_b, vvec, coverage,
                                                     enc, wsb, out);
}

// Round 6
// 63.905 us; speedup vs baseline: 1.7544x; 1.7544x over previous
//
#include <hip/hip_runtime.h>
#include <hip/hip_bf16.h>
#include <math.h>

// Problem constants: B=16, L=96, H=128.
#define BB 16
#define LL 96
#define HH 128

typedef __attribute__((ext_vector_type(8))) short short8;
typedef __attribute__((ext_vector_type(4))) float f32x4;

// Only slice kh=63 of attn_conv_w matters (input height 1, SAME pad (63,64)).
// Only slice kw=63 of cvg_conv_w matters (input width 1, SAME pad (63,64)).
//
// ws byte offsets:
//  WS_W : frag-major bf16 W. frag f=((i*4+s)*6+ot): 64 lanes x 16B      -> 2,359,296 B
//  WS_E : dual-copy bf16 padded enc rows [b][i][272 u32]                 -> 1,671,168 B
//  WS_DEC / WS_CVG / WS_SC : fp32 dec_f / cvg_f / scores
//  WS_P : fp32 partials [kc][b][o][w]                                    -> 25,165,824 B
#define WS_W_OFF   0
#define WS_E_OFF   2359296
#define WS_DEC_OFF 4030464
#define WS_CVG_OFF 4038656
#define WS_SC_OFF  4044800
#define WS_P_OFF   4050944

// ---------------- P: frag-major W->bf16, dual-copy enc rows, dec_f, cvg_f ----------------
__global__ __launch_bounds__(256) void prep_kernel(
        const float* __restrict__ hidden,
        const float* __restrict__ enc,
        const float* __restrict__ coverage,
        const float* __restrict__ attn_w,
        const float* __restrict__ cvg_w,
        const float* __restrict__ cvg_b,
        const float* __restrict__ dec_w,
        const float* __restrict__ dec_b,
        char* __restrict__ wsb) {
    const int bid = blockIdx.x;
    const int tid = threadIdx.x;
    if (bid < 96) {
        // W slice kh=63, frag-major: frag ((i*4+s)*6+ot), lane (hi*16+lo), elem j
        //  holds W[o=ot*16+lo][m=s*32+hi*8+j]
        const int i = bid;
        unsigned short* wout = (unsigned short*)(wsb + WS_W_OFF);
        for (int idx = tid; idx < LL * HH; idx += 256) {
            const int o = idx >> 7, m = idx & 127;
            float v = attn_w[(((size_t)o * LL + i) * HH + 63) * HH + m];
            __hip_bfloat16 h = __float2bfloat16(v);
            const int f = (i * 4 + (m >> 5)) * 6 + (o >> 4);
            const int off = (((m >> 3) & 3) * 16 + (o & 15)) * 8 + (m & 7);
            wout[(size_t)f * 512 + off] = *(unsigned short*)&h;
        }
    } else if (bid < 112) {
        // dual-copy bf16 padded enc rows, per row 272 u32:
        //  [0..127]   w0[q] = (e(2q),   e(2q+1))
        //  [129..256] w1[q] = (e(2q+1), e(2q+2));  e(t)=enc[t-63] for t in [63,191) else 0
        const int b = bid - 96;
        unsigned int* eout = (unsigned int*)(wsb + WS_E_OFF) + (size_t)b * LL * 272;
        const float* esrc = enc + (size_t)b * LL * HH;
        for (int idx = tid; idx < LL * 272; idx += 256) {
            const int i = idx / 272, c = idx % 272;
            int t0 = -1, t1 = -1;
            if (c < 128) { t0 = 2 * c; t1 = 2 * c + 1; }
            else if (c >= 129 && c < 257) { int q = c - 129; t0 = 2 * q + 1; t1 = 2 * q + 2; }
            unsigned int lo16 = 0, hi16 = 0;
            if (t0 >= 63 && t0 < 191) {
                __hip_bfloat16 h = __float2bfloat16(esrc[i * HH + t0 - 63]);
                lo16 = *(unsigned short*)&h;
            }
            if (t1 >= 63 && t1 < 191) {
                __hip_bfloat16 h = __float2bfloat16(esrc[i * HH + t1 - 63]);
                hi16 = *(unsigned short*)&h;
            }
            eout[idx] = lo16 | (hi16 << 16);
        }
    } else {
        const int b = bid - 112;
        float* decf = (float*)(wsb + WS_DEC_OFF);
        float* cvgf = (float*)(wsb + WS_CVG_OFF);
        __shared__ float hid[HH];
        __shared__ float cov[LL];
        if (tid < HH) hid[tid] = hidden[b * HH + tid];
        if (tid < LL) cov[tid] = coverage[b * LL + tid];
        __syncthreads();
        if (tid < HH) {
            float acc = dec_b[tid];
            for (int k = 0; k < HH; ++k) acc += hid[k] * dec_w[tid * HH + k];
            decf[b * HH + tid] = acc;
        } else if (tid < HH + LL) {
            const int t = tid - HH;
            float a2 = cvg_b[t];
            for (int i2 = 0; i2 < LL; ++i2)
                a2 += cov[i2] * cvg_w[((size_t)t * LL + i2) * HH + 63];
            cvgf[b * LL + t] = a2;
        }
    }
}

// ---------------- M: all-register bf16 MFMA — no LDS, no barriers ----------------
// grid (kc=32, b=16) x 256 thr = 4 waves: wave = (oh=wg>>1: 3 o-tiles) x (wh=wg&1: 4 w-tiles).
// A-frags: 1 coalesced dwordx4 per frag from frag-major W (L2-hot).
// B-frags: 4 aligned u32 loads per window from dual-copy E (L2-hot).
__global__ __launch_bounds__(256) void mfma_kernel(char* __restrict__ wsb) {
    const int kc = blockIdx.x;   // 0..31
    const int b  = blockIdx.y;   // 0..15
    const int tid  = threadIdx.x;
    const int lane = tid & 63;
    const int wg   = tid >> 6;
    const int lo   = lane & 15;
    const int hi   = lane >> 4;  // 0..3
    const int oh   = wg >> 1;    // o-half: tiles oh*3..oh*3+2
    const int wh   = wg & 1;     // w-half: cols wh*64..wh*64+63

    const unsigned short* Wf = (const unsigned short*)(wsb + WS_W_OFF);
    const unsigned int*   Eb = (const unsigned int*)(wsb + WS_E_OFF)
                               + ((size_t)b * LL + kc * 3) * 272;
    float* Pp = (float*)(wsb + WS_P_OFF);

    f32x4 acc[3][4];
#pragma unroll
    for (int t = 0; t < 3; ++t)
#pragma unroll
        for (int wt = 0; wt < 4; ++wt) acc[t][wt] = f32x4{0.f, 0.f, 0.f, 0.f};

#pragma unroll
    for (int r = 0; r < 3; ++r) {
        const unsigned int* erow = Eb + r * 272 + ((lo & 1) ? 129 : 0);
        const unsigned short* frow = Wf + (size_t)((kc * 3 + r) * 4) * 6 * 512 + lane * 8;
#pragma unroll
        for (int s = 0; s < 4; ++s) {
            short8 af[3];
#pragma unroll
            for (int t = 0; t < 3; ++t)
                af[t] = *(const short8*)(frow + (s * 6 + oh * 3 + t) * 512);
#pragma unroll
            for (int wt = 0; wt < 4; ++wt) {
                const int t0 = s * 32 + wh * 64 + wt * 16 + hi * 8 + lo;
                const unsigned int* a = erow + (t0 >> 1);
                union { uint4 u; short8 s8; } bf;
                bf.u.x = a[0]; bf.u.y = a[1]; bf.u.z = a[2]; bf.u.w = a[3];
#pragma unroll
                for (int t = 0; t < 3; ++t)
                    acc[t][wt] = __builtin_amdgcn_mfma_f32_16x16x32_bf16(
                        af[t], bf.s8, acc[t][wt], 0, 0, 0);
            }
        }
    }

    // fp32 partial store, [kc][b][o][w] (round-3 format)
    float* dst = Pp + (size_t)(kc * BB + b) * LL * HH;
#pragma unroll
    for (int t = 0; t < 3; ++t)
#pragma unroll
        for (int wt = 0; wt < 4; ++wt) {
            const int w = wh * 64 + wt * 16 + lo;
#pragma unroll
            for (int rr = 0; rr < 4; ++rr) {
                const int o = (oh * 3 + t) * 16 + hi * 4 + rr;
                dst[o * HH + w] = acc[t][wt][rr];
            }
        }
}

// ---------------- R: sum partials + bias/dec/cvg -> tanh -> dot v -> scores ----------------
__global__ __launch_bounds__(128) void reduce_kernel(
        const float* __restrict__ attn_b,
        const float* __restrict__ vvec,
        char* __restrict__ wsb) {
    const int o = blockIdx.x;   // 0..95
    const int b = blockIdx.y;   // 0..15
    const int h = threadIdx.x;  // 0..127
    const float* p = (const float*)(wsb + WS_P_OFF) + ((size_t)b * LL + o) * HH + h;
    const float* dec = (const float*)(wsb + WS_DEC_OFF);
    const float* cvg = (const float*)(wsb + WS_CVG_OFF);
    float* sc_ws = (float*)(wsb + WS_SC_OFF);

    float sum = 0.f;
#pragma unroll
    for (int kc = 0; kc < 32; ++kc) sum += p[(size_t)kc * BB * LL * HH];
    float ef = sum + attn_b[o] + dec[b * HH + h] + cvg[b * LL + o];
    float s = tanhf(ef) * vvec[b * HH + h];
#pragma unroll
    for (int off = 32; off > 0; off >>= 1) s += __shfl_down(s, off, 64);
    __shared__ float r2[2];
    if ((h & 63) == 0) r2[h >> 6] = s;
    __syncthreads();
    if (h == 0) sc_ws[b * LL + o] = r2[0] + r2[1];
}

// ---------------- F: softmax + outputs ----------------
__global__ void finalize_kernel(const float* __restrict__ ws_scores,
                                const float* __restrict__ coverage,
                                const float* __restrict__ enc,
                                float* __restrict__ out) {
    int b = blockIdx.x;
    int t = threadIdx.x;  // 0..127
    __shared__ float sc[LL];
    __shared__ float at[LL];
    if (t < LL) sc[t] = ws_scores[b * LL + t];
    __syncthreads();

    float mx = -1e30f;
    for (int l = 0; l < LL; ++l) mx = fmaxf(mx, sc[l]);
    float sum = 0.f;
    for (int l = 0; l < LL; ++l) sum += expf(sc[l] - mx);

    if (t < LL) {
        float a = expf(sc[t] - mx) / sum;
        at[t] = a;
        out[BB * HH + b * LL + t] = a;                                   // attn
        out[BB * HH + BB * LL + b * LL + t] = coverage[b * LL + t] + a;  // new_coverage
    }
    __syncthreads();

    float ctx = 0.f;
#pragma unroll 8
    for (int l = 0; l < LL; ++l) ctx += at[l] * enc[((size_t)b * LL + l) * HH + t];
    out[b * HH + t] = ctx;                                               // context
}

extern "C" void kernel_launch(void* const* d_in, const int* in_sizes, int n_in,
                              void* d_out, int out_size, void* d_ws, size_t ws_size,
                              hipStream_t stream) {
    const float* hidden   = (const float*)d_in[0];
    const float* enc      = (const float*)d_in[1];
    const float* coverage = (const float*)d_in[2];
    const float* attn_w   = (const float*)d_in[3];
    const float* attn_b   = (const float*)d_in[4];
    const float* cvg_w    = (const float*)d_in[5];
    const float* cvg_b    = (const float*)d_in[6];
    const float* dec_w    = (const float*)d_in[7];
    const float* dec_b    = (const float*)d_in[8];
    const float* vvec     = (const float*)d_in[9];
    float* out = (float*)d_out;
    char* wsb = (char*)d_ws;

    prep_kernel<<<128, 256, 0, stream>>>(hidden, enc, coverage, attn_w,
                                         cvg_w, cvg_b, dec_w, dec_b, wsb);
    mfma_kernel<<<dim3(32, BB), 256, 0, stream>>>(wsb);
    reduce_kernel<<<dim3(LL, BB), 128, 0, stream>>>(attn_b, vvec, wsb);
    finalize_kernel<<<BB, HH, 0, stream>>>((const float*)(wsb + WS_SC_OFF),
                                           coverage, enc, out);
}

// Round 8
// 45.519 us; speedup vs baseline: 2.4631x; 1.4039x over previous
//
#include <hip/hip_runtime.h>
#include <hip/hip_bf16.h>
#include <hip/hip_fp16.h>
#include <math.h>

// Problem constants: B=16, L=96, H=128.
#define BB 16
#define LL 96
#define HH 128

typedef __attribute__((ext_vector_type(8))) short short8;
typedef __attribute__((ext_vector_type(4))) float f32x4;

// Only slice kh=63 of attn_conv_w matters (input height 1, SAME pad (63,64)).
// Only slice kw=63 of cvg_conv_w matters (input width 1, SAME pad (63,64)).
//
// ws layout (float units) — round-3 layout; WS_P now holds fp16 (uses half the slots):
#define WS_W    0              // 589824 float-slots = 1179648 shorts: bf16 W [i][o][e] (e pre-XOR-swizzled)
#define WS_E    589824         // 16*96*256 fp32 zero-padded enc rows [b][i][256] (t=63..190 = enc)
#define WS_DEC  983040         // 16*128
#define WS_CVG  985088         // 16*96
#define WS_SC   986624         // 16*96
#define WS_P    988160         // fp16 partials [kc][b][o][w]: 32*16*96*128 halves

// ---------------- P1: convert W->bf16 (swizzled), build padded enc, dec_f, cvg_f ----------------
__global__ __launch_bounds__(256) void prep_kernel(
        const float* __restrict__ hidden,
        const float* __restrict__ enc,
        const float* __restrict__ coverage,
        const float* __restrict__ attn_w,
        const float* __restrict__ cvg_w,
        const float* __restrict__ cvg_b,
        const float* __restrict__ dec_w,
        const float* __restrict__ dec_b,
        float* __restrict__ ws) {
    const int bid = blockIdx.x;
    const int tid = threadIdx.x;
    if (bid < 96) {
        // W slice: ws_W[i][o][e] = bf16(attn_w[o][i][63][ e ^ ((o&7)<<3) ])
        const int i = bid;
        unsigned short* wout = (unsigned short*)(ws + WS_W);
        for (int idx = tid; idx < LL * HH; idx += 256) {
            const int o = idx >> 7, e = idx & 127;
            const int esrc = e ^ ((o & 7) << 3);
            float v = attn_w[(((size_t)o * LL + i) * HH + 63) * HH + esrc];
            __hip_bfloat16 h = __float2bfloat16(v);
            wout[(size_t)i * LL * HH + idx] = *(unsigned short*)&h;
        }
    } else if (bid < 112) {
        // padded enc rows: ws_E[b][i][t] = enc[b][i][t-63] for t in [63,191), else 0
        const int b = bid - 96;
        float* eout = ws + WS_E + (size_t)b * LL * 256;
        for (int idx = tid; idx < LL * 256; idx += 256) {
            const int i = idx >> 8, t = idx & 255;
            eout[idx] = (t >= 63 && t < 191) ? enc[((size_t)b * LL + i) * HH + (t - 63)] : 0.f;
        }
    } else {
        const int b = bid - 112;
        __shared__ float hid[HH];
        __shared__ float cov[LL];
        if (tid < HH) hid[tid] = hidden[b * HH + tid];
        if (tid < LL) cov[tid] = coverage[b * LL + tid];
        __syncthreads();
        if (tid < HH) {
            float acc = dec_b[tid];
            for (int k = 0; k < HH; ++k) acc += hid[k] * dec_w[tid * HH + k];
            ws[WS_DEC + b * HH + tid] = acc;
        } else if (tid < HH + LL) {
            const int t = tid - HH;
            float a2 = cvg_b[t];
            for (int i2 = 0; i2 < LL; ++i2)
                a2 += cov[i2] * cvg_w[((size_t)t * LL + i2) * HH + 63];
            ws[WS_CVG + b * LL + t] = a2;
        }
    }
}

// ---------------- M: split-K implicit-im2col bf16 MFMA GEMM (round-3 structure) ----------------
// grid (kc=32, b=16); 256 threads = 4 waves; wave wg covers w in [wg*32, wg*32+32).
// Each wave: 6 o-tiles x 2 w-tiles of 16x16x32 MFMA; k-chunk = 3 i-rows = 12 k-steps.
__global__ __launch_bounds__(256) void mfma_kernel(float* __restrict__ ws) {
    const int kc = blockIdx.x;   // 0..31
    const int b  = blockIdx.y;   // 0..15
    const int tid  = threadIdx.x;
    const int lane = tid & 63;
    const int wg   = tid >> 6;   // wave id 0..3
    const int lo   = lane & 15;
    const int hi   = lane >> 4;  // 0..3

    __shared__ __align__(16) short Abuf[LL * HH];  // 24KB, bf16 W[o][e] (e swizzled)
    __shared__ __align__(16) float Ebuf[256];      // padded enc row (fp32)

    f32x4 acc[6][2];
#pragma unroll
    for (int a = 0; a < 6; ++a)
#pragma unroll
        for (int c = 0; c < 2; ++c) acc[a][c] = f32x4{0.f, 0.f, 0.f, 0.f};

    const short* wsrc = (const short*)(ws + WS_W);
    const float* esrc = ws + WS_E + (size_t)b * LL * 256;

    for (int ii = 0; ii < 3; ++ii) {
        const int ig = kc * 3 + ii;   // global i row
        __syncthreads();
        // stage A: 12288 shorts = 1536 short8, 6 per thread
        {
            const short8* s8 = (const short8*)(wsrc + (size_t)ig * LL * HH);
            short8* d8 = (short8*)Abuf;
#pragma unroll
            for (int t = 0; t < 6; ++t) d8[tid + t * 256] = s8[tid + t * 256];
            if (tid < 64)
                ((float4*)Ebuf)[tid] = ((const float4*)(esrc + ig * 256))[tid];
        }
        __syncthreads();

#pragma unroll
        for (int s = 0; s < 4; ++s) {      // k-step within i (m0 = 32s)
            short8 af[6];
#pragma unroll
            for (int ot = 0; ot < 6; ++ot) {
                const int o = ot * 16 + lo;
                const int idx8 = o * 16 + (((s << 2) + hi) ^ (o & 7));
                af[ot] = ((const short8*)Abuf)[idx8];
            }
#pragma unroll
            for (int wt = 0; wt < 2; ++wt) {
                const int t0 = s * 32 + hi * 8 + wg * 32 + wt * 16 + lo;  // <= 247
                union { short8 s8; __hip_bfloat16 h[8]; } bf;
#pragma unroll
                for (int j = 0; j < 8; ++j) bf.h[j] = __float2bfloat16(Ebuf[t0 + j]);
#pragma unroll
                for (int ot = 0; ot < 6; ++ot)
                    acc[ot][wt] = __builtin_amdgcn_mfma_f32_16x16x32_bf16(
                        af[ot], bf.s8, acc[ot][wt], 0, 0, 0);
            }
        }
    }

    // write split-K partials (fp16, [kc][b][o][w], w lane-consecutive -> coalesced)
    __half* dst = (__half*)(ws + WS_P) + (size_t)(kc * BB + b) * LL * HH;
#pragma unroll
    for (int ot = 0; ot < 6; ++ot)
#pragma unroll
        for (int wt = 0; wt < 2; ++wt)
#pragma unroll
            for (int r = 0; r < 4; ++r) {
                const int o = ot * 16 + hi * 4 + r;     // C/D: row=(lane>>4)*4+reg
                const int w = wg * 32 + wt * 16 + lo;   //      col=lane&15
                dst[o * HH + w] = __float2half(acc[ot][wt][r]);
            }
}

// ---------------- R: sum partials + bias/dec/cvg -> tanh -> dot v -> scores ----------------
__global__ __launch_bounds__(128) void reduce_kernel(
        const float* __restrict__ attn_b,
        const float* __restrict__ vvec,
        float* __restrict__ ws) {
    const int o = blockIdx.x;   // 0..95
    const int b = blockIdx.y;   // 0..15
    const int h = threadIdx.x;  // 0..127
    const __half* p = (const __half*)(ws + WS_P) + ((size_t)b * LL + o) * HH + h;
    float sum = 0.f;
#pragma unroll
    for (int kc = 0; kc < 32; ++kc)
        sum += __half2float(p[(size_t)kc * BB * LL * HH]);
    float ef = sum + attn_b[o] + ws[WS_DEC + b * HH + h] + ws[WS_CVG + b * LL + o];
    float s = tanhf(ef) * vvec[b * HH + h];
#pragma unroll
    for (int off = 32; off > 0; off >>= 1) s += __shfl_down(s, off, 64);
    __shared__ float r2[2];
    if ((h & 63) == 0) r2[h >> 6] = s;
    __syncthreads();
    if (h == 0) ws[WS_SC + b * LL + o] = r2[0] + r2[1];
}

// ---------------- F: softmax + outputs ----------------
__global__ void finalize_kernel(const float* __restrict__ ws_scores,
                                const float* __restrict__ coverage,
                                const float* __restrict__ enc,
                                float* __restrict__ out) {
    int b = blockIdx.x;
    int t = threadIdx.x;  // 0..127
    __shared__ float sc[LL];
    __shared__ float at[LL];
    if (t < LL) sc[t] = ws_scores[b * LL + t];
    __syncthreads();

    float mx = -1e30f;
    for (int l = 0; l < LL; ++l) mx = fmaxf(mx, sc[l]);
    float sum = 0.f;
    for (int l = 0; l < LL; ++l) sum += expf(sc[l] - mx);

    if (t < LL) {
        float a = expf(sc[t] - mx) / sum;
        at[t] = a;
        out[BB * HH + b * LL + t] = a;                                   // attn
        out[BB * HH + BB * LL + b * LL + t] = coverage[b * LL + t] + a;  // new_coverage
    }
    __syncthreads();

    float ctx = 0.f;
#pragma unroll 8
    for (int l = 0; l < LL; ++l) ctx += at[l] * enc[((size_t)b * LL + l) * HH + t];
    out[b * HH + t] = ctx;                                               // context
}

extern "C" void kernel_launch(void* const* d_in, const int* in_sizes, int n_in,
                              void* d_out, int out_size, void* d_ws, size_t ws_size,
                              hipStream_t stream) {
    const float* hidden   = (const float*)d_in[0];
    const float* enc      = (const float*)d_in[1];
    const float* coverage = (const float*)d_in[2];
    const float* attn_w   = (const float*)d_in[3];
    const float* attn_b   = (const float*)d_in[4];
    const float* cvg_w    = (const float*)d_in[5];
    const float* cvg_b    = (const float*)d_in[6];
    const float* dec_w    = (const float*)d_in[7];
    const float* dec_b    = (const float*)d_in[8];
    const float* vvec     = (const float*)d_in[9];
    float* out = (float*)d_out;
    float* ws = (float*)d_ws;

    prep_kernel<<<128, 256, 0, stream>>>(hidden, enc, coverage, attn_w,
                                         cvg_w, cvg_b, dec_w, dec_b, ws);
    mfma_kernel<<<dim3(32, BB), 256, 0, stream>>>(ws);
    reduce_kernel<<<dim3(LL, BB), 128, 0, stream>>>(attn_b, vvec, ws);
    finalize_kernel<<<BB, HH, 0, stream>>>(ws + WS_SC, coverage, enc, out);
}